// Round 4
// baseline (1798.251 us; speedup 1.0000x reference)
//
#include <hip/hip_runtime.h>

#define H 184
#define MDH 16
#define L1D 188
#define NPART 8
#define RW 5          // accumulator row: 4 float features + 1 float count

// ---------------- zero init ----------------
__global__ void zero_kernel(float* __restrict__ p, int n) {
    int i = blockIdx.x * blockDim.x + threadIdx.x;
    if (i < n) p[i] = 0.0f;
}

// ---------------- edge pass: privatized fire-and-forget float atomics ----------------
// acc layout: [pmask+1][N][RW]. p = blockIdx & pmask keeps each partition's 4 MB
// accumulator resident in (ideally) one XCD's L2 — no cross-XCD line ping-pong.
__global__ __launch_bounds__(256) void edge_priv_kernel(
        const float* __restrict__ nf,   // (N,6)
        const int*   __restrict__ ei,   // (2,E)
        const float* __restrict__ ew,   // (E,)
        float* __restrict__ acc,
        int N, int E, int pmask) {
    int e = blockIdx.x * blockDim.x + threadIdx.x;
    if (e >= E) return;
    int p = blockIdx.x & pmask;
    int src = ei[e];
    int dst = ei[E + e];
    float w = ew[e];
    const float2* xr = (const float2*)(nf + (size_t)src * 6);  // 8B-aligned (stride 24B)
    float2 x01 = xr[0];
    float2 x23 = xr[1];
    float* base = acc + ((size_t)p * N + dst) * RW;
    atomicAdd(base + 0, x01.x * w);
    atomicAdd(base + 1, x01.y * w);
    atomicAdd(base + 2, x23.x * w);
    atomicAdd(base + 3, x23.y * w);
    atomicAdd(base + 4, 1.0f);
}

// ---------------- reduce partitions: agg[n] = sum_p acc[p][n][0..3], deg[n] = sum counts ----------------
__global__ __launch_bounds__(256) void reduce_kernel(
        const float* __restrict__ acc, float* __restrict__ agg,
        float* __restrict__ deg, int N, int nparts) {
    int n = blockIdx.x * blockDim.x + threadIdx.x;
    if (n >= N) return;
    float a0 = 0.f, a1 = 0.f, a2 = 0.f, a3 = 0.f, d = 0.f;
    for (int p = 0; p < nparts; ++p) {
        const float* r = acc + ((size_t)p * N + n) * RW;
        a0 += r[0]; a1 += r[1]; a2 += r[2]; a3 += r[3]; d += r[4];
    }
    ((float4*)agg)[n] = make_float4(a0, a1, a2, a3);
    deg[n] = d;
}

// ---------------- per-node dense layer + global feature max ----------------
__global__ __launch_bounds__(192) void node_kernel(
        const float* __restrict__ nf,
        const float* __restrict__ agg,
        const float* __restrict__ deg,
        const float* __restrict__ W_rel, const float* __restrict__ b_rel,
        const float* __restrict__ W_root,
        const int*   __restrict__ centerp,
        unsigned int* __restrict__ xmax_bits,
        float* __restrict__ h0,
        int N, int nodes_per_block) {
    int j = threadIdx.x;
    if (j >= H) return;
    int center = *centerp;
    int n0 = blockIdx.x * nodes_per_block;
    int n1 = n0 + nodes_per_block;
    if (n1 > N) n1 = N;

    float wr0 = W_rel[0 * H + j], wr1 = W_rel[1 * H + j];
    float wr2 = W_rel[2 * H + j], wr3 = W_rel[3 * H + j];
    float wo0 = W_root[0 * H + j], wo1 = W_root[1 * H + j];
    float wo2 = W_root[2 * H + j], wo3 = W_root[3 * H + j];
    float b = b_rel[j];

    float mx = 0.0f;
    for (int n = n0; n < n1; ++n) {
        float4 a = ((const float4*)agg)[n];
        float inv = 1.0f / fmaxf(deg[n], 1.0f);
        const float* xr = nf + (size_t)n * 6;
        float v = b
                + (a.x * inv) * wr0 + (a.y * inv) * wr1
                + (a.z * inv) * wr2 + (a.w * inv) * wr3
                + xr[0] * wo0 + xr[1] * wo1 + xr[2] * wo2 + xr[3] * wo3;
        v = fmaxf(v, 0.0f);
        mx = fmaxf(mx, v);
        if (n == center) h0[j] = v;
    }
    atomicMax(xmax_bits + j, __float_as_uint(mx));  // relu out >= 0
}

// ---------------- tiny head MLP, one block ----------------
__global__ __launch_bounds__(256) void final_kernel(
        const float* __restrict__ nf,
        const int*   __restrict__ centerp,
        const unsigned int* __restrict__ xmax_bits,
        const float* __restrict__ h0,
        const float* __restrict__ W2,  const float* __restrict__ b2,
        const float* __restrict__ W21, const float* __restrict__ b21,
        const float* __restrict__ W1,  const float* __restrict__ b1,
        const float* __restrict__ W4,  const float* __restrict__ b4,
        float* __restrict__ out) {
    __shared__ float gin[H + MDH];
    __shared__ float md0[MDH];
    __shared__ float g1[L1D];
    int t = threadIdx.x;
    int center = *centerp;

    if (t < H) gin[t] = h0[t] - __uint_as_float(xmax_bits[t]);
    if (t < MDH) {
        float m0 = nf[(size_t)center * 6 + 4];
        float m1 = nf[(size_t)center * 6 + 5];
        md0[t] = fmaxf(m0 * W2[t] + m1 * W2[MDH + t] + b2[t], 0.0f);
    }
    __syncthreads();
    if (t < MDH) {
        float s = b21[t];
        for (int k = 0; k < MDH; ++k) s += md0[k] * W21[k * MDH + t];
        gin[H + t] = fmaxf(s, 0.0f);
    }
    __syncthreads();
    if (t < L1D) {
        float s = b1[t];
        for (int k = 0; k < H + MDH; ++k) s += gin[k] * W1[k * L1D + t];
        g1[t] = fmaxf(s, 0.0f);
    }
    __syncthreads();
    if (t < 5) {
        float s = b4[t];
        for (int k = 0; k < L1D; ++k) s += g1[k] * W4[k * 5 + t];
        out[t] = s;
    }
}

extern "C" void kernel_launch(void* const* d_in, const int* in_sizes, int n_in,
                              void* d_out, int out_size, void* d_ws, size_t ws_size,
                              hipStream_t stream) {
    const float* nf      = (const float*)d_in[0];
    const int*   ei      = (const int*)  d_in[1];
    const float* ew      = (const float*)d_in[2];
    const int*   centerp = (const int*)  d_in[3];
    const float* W_rel   = (const float*)d_in[4];
    const float* b_rel   = (const float*)d_in[5];
    const float* W_root  = (const float*)d_in[6];
    const float* W2      = (const float*)d_in[7];
    const float* b2      = (const float*)d_in[8];
    const float* W21     = (const float*)d_in[9];
    const float* b21     = (const float*)d_in[10];
    const float* W1      = (const float*)d_in[11];
    const float* b1      = (const float*)d_in[12];
    const float* W4      = (const float*)d_in[13];
    const float* b4      = (const float*)d_in[14];
    float* out = (float*)d_out;

    const int N = in_sizes[0] / 6;
    const int E = in_sizes[1] / 2;

    // choose partition count by available workspace
    // need (floats): nparts*N*RW (acc) + H (xmax) + 4N (agg) + N (deg) + H (h0)
    int nparts = NPART;
    while (nparts > 1 &&
           ((size_t)nparts * N * RW + 2 * H + 5 * (size_t)N) * 4 > ws_size)
        nparts >>= 1;
    int pmask = nparts - 1;

    // workspace layout (floats): acc | xmax | agg | deg | h0
    float*        acc  = (float*)d_ws;
    unsigned int* xmax = (unsigned int*)(acc + (size_t)nparts * N * RW);
    float*        agg  = (float*)(xmax + H);
    float*        deg  = agg + (size_t)N * 4;
    float*        h0   = deg + N;

    // zero acc + xmax (contiguous)
    int zero_n = nparts * N * RW + H;
    zero_kernel<<<(zero_n + 255) / 256, 256, 0, stream>>>(acc, zero_n);

    edge_priv_kernel<<<(E + 255) / 256, 256, 0, stream>>>(nf, ei, ew, acc, N, E, pmask);

    reduce_kernel<<<(N + 255) / 256, 256, 0, stream>>>(acc, agg, deg, N, nparts);

    const int blocks = 1024;
    const int npb = (N + blocks - 1) / blocks;
    node_kernel<<<blocks, 192, 0, stream>>>(nf, agg, deg, W_rel, b_rel, W_root,
                                            centerp, xmax, h0, N, npb);
    final_kernel<<<1, 256, 0, stream>>>(nf, centerp, xmax, h0,
                                        W2, b2, W21, b21, W1, b1, W4, b4, out);
}

// Round 5
// 628.145 us; speedup vs baseline: 2.8628x; 2.8628x over previous
//
#include <hip/hip_runtime.h>

#define H 184
#define MDH 16
#define L1D 188
#define BBITS 8
#define BSZ 256           // nodes per bucket (2^BBITS)
#define NB 1024           // blocks in hist/partition (must match in both)
#define KMAX 1024

// ---------------- zero init ----------------
__global__ void zero_kernel(int* __restrict__ p, int n) {
    int i = blockIdx.x * blockDim.x + threadIdx.x;
    if (i < n) p[i] = 0;
}

// ---------------- phase 1: per-block bucket histogram (LDS atomics only) ----------------
__global__ __launch_bounds__(256) void hist_kernel(
        const int* __restrict__ ei, int* __restrict__ hist, int E, int K, int epb) {
    __shared__ int cnt[KMAX];
    int b = blockIdx.x;
    for (int k = threadIdx.x; k < K; k += 256) cnt[k] = 0;
    __syncthreads();
    int e0 = b * epb;
    int e1 = min(E, e0 + epb);
    for (int e = e0 + threadIdx.x; e < e1; e += 256) {
        int dst = ei[E + e];
        atomicAdd(&cnt[dst >> BBITS], 1);
    }
    __syncthreads();
    for (int k = threadIdx.x; k < K; k += 256)
        hist[(size_t)k * NB + b] = cnt[k];
}

// ---------------- phase 2a: per-bucket exclusive scan over blocks ----------------
__global__ __launch_bounds__(256) void col_scan_kernel(
        int* __restrict__ hist, int* __restrict__ tsum) {
    __shared__ int s[256];
    int k = blockIdx.x;
    int t = threadIdx.x;
    int* row = hist + (size_t)k * NB;
    int cbase = 0;
    for (int c = 0; c < NB; c += 256) {
        int v = row[c + t];
        s[t] = v;
        __syncthreads();
        for (int st = 1; st < 256; st <<= 1) {
            int u = (t >= st) ? s[t - st] : 0;
            __syncthreads();
            s[t] += u;
            __syncthreads();
        }
        row[c + t] = s[t] - v + cbase;     // exclusive + carry
        int total = s[255];                // stable after last sync
        __syncthreads();                   // protect s before next chunk
        cbase += total;
    }
    if (t == 0) tsum[k] = cbase;
}

// ---------------- phase 2b: exclusive scan of bucket totals ----------------
__global__ __launch_bounds__(1024) void top_scan_kernel(
        const int* __restrict__ tsum, int* __restrict__ bstart, int K) {
    __shared__ int s[1024];
    int t = threadIdx.x;
    int v = (t < K) ? tsum[t] : 0;
    s[t] = v;
    __syncthreads();
    for (int st = 1; st < 1024; st <<= 1) {
        int u = (t >= st) ? s[t - st] : 0;
        __syncthreads();
        s[t] += u;
        __syncthreads();
    }
    if (t < K) bstart[t] = s[t] - v;
    if (t == K - 1) bstart[K] = s[t];
}

// ---------------- phase 3: partition edges into bucket runs ----------------
// Same block->edge-range mapping as hist_kernel. Slot allocation via LDS
// counters seeded from the scans — zero global atomics. Each block's write
// frontier is K lines (~50 KB) -> L2-resident -> stores merge (no 64B-line
// write amplification).
__global__ __launch_bounds__(256) void partition_kernel(
        const int* __restrict__ ei, const float* __restrict__ ew,
        const int* __restrict__ hist, const int* __restrict__ bstart,
        uint2* __restrict__ sorted, int E, int K, int epb) {
    __shared__ int lcnt[KMAX];
    int b = blockIdx.x;
    for (int k = threadIdx.x; k < K; k += 256)
        lcnt[k] = bstart[k] + hist[(size_t)k * NB + b];
    __syncthreads();
    int e0 = b * epb;
    int e1 = min(E, e0 + epb);
    for (int e = e0 + threadIdx.x; e < e1; e += 256) {
        int dst = ei[E + e];
        int src = ei[e];
        float w = ew[e];
        int k = dst >> BBITS;
        int pos = atomicAdd(&lcnt[k], 1);
        sorted[pos] = make_uint2(((unsigned)(dst & (BSZ - 1)) << 24) | (unsigned)src,
                                 __float_as_uint(w));
    }
}

// ---------------- phase 4: per-bucket accumulate in LDS ----------------
__global__ __launch_bounds__(256) void bucket_acc_kernel(
        const float* __restrict__ nf, const uint2* __restrict__ sorted,
        const int* __restrict__ bstart,
        float* __restrict__ agg, float* __restrict__ deg, int N) {
    __shared__ float acc[BSZ * 5];
    int k = blockIdx.x;
    int t = threadIdx.x;
    for (int i = t; i < BSZ * 5; i += 256) acc[i] = 0.0f;
    __syncthreads();
    int i1 = bstart[k + 1];
    for (int i = bstart[k] + t; i < i1; i += 256) {
        uint2 r = sorted[i];
        unsigned src = r.x & 0xFFFFFFu;
        unsigned dl = r.x >> 24;
        float w = __uint_as_float(r.y);
        const float2* xr = (const float2*)(nf + (size_t)src * 6);
        float2 x01 = xr[0];
        float2 x23 = xr[1];
        float* a = acc + dl * 5;
        atomicAdd(a + 0, x01.x * w);
        atomicAdd(a + 1, x01.y * w);
        atomicAdd(a + 2, x23.x * w);
        atomicAdd(a + 3, x23.y * w);
        atomicAdd(a + 4, 1.0f);
    }
    __syncthreads();
    int n = (k << BBITS) + t;
    if (n < N) {
        ((float4*)agg)[n] = make_float4(acc[t * 5], acc[t * 5 + 1],
                                        acc[t * 5 + 2], acc[t * 5 + 3]);
        deg[n] = acc[t * 5 + 4];
    }
}

// ---------------- fallback: global-atomic scatter (ws too small / K too big) ----------------
__global__ __launch_bounds__(256) void edge_atomic_kernel(
        const float* __restrict__ nf, const int* __restrict__ ei,
        const float* __restrict__ ew, float* __restrict__ agg,
        float* __restrict__ deg, int E) {
    int e = blockIdx.x * blockDim.x + threadIdx.x;
    if (e >= E) return;
    int src = ei[e];
    int dst = ei[E + e];
    float w = ew[e];
    const float2* xr = (const float2*)(nf + (size_t)src * 6);
    float2 x01 = xr[0];
    float2 x23 = xr[1];
    float* a = agg + (size_t)dst * 4;
    atomicAdd(a + 0, x01.x * w);
    atomicAdd(a + 1, x01.y * w);
    atomicAdd(a + 2, x23.x * w);
    atomicAdd(a + 3, x23.y * w);
    atomicAdd(deg + dst, 1.0f);
}

// ---------------- per-node dense layer + global feature max ----------------
__global__ __launch_bounds__(192) void node_kernel(
        const float* __restrict__ nf,
        const float* __restrict__ agg,
        const float* __restrict__ deg,
        const float* __restrict__ W_rel, const float* __restrict__ b_rel,
        const float* __restrict__ W_root,
        const int*   __restrict__ centerp,
        unsigned int* __restrict__ xmax_bits,
        float* __restrict__ h0,
        int N, int nodes_per_block) {
    int j = threadIdx.x;
    if (j >= H) return;
    int center = *centerp;
    int n0 = blockIdx.x * nodes_per_block;
    int n1 = n0 + nodes_per_block;
    if (n1 > N) n1 = N;

    float wr0 = W_rel[0 * H + j], wr1 = W_rel[1 * H + j];
    float wr2 = W_rel[2 * H + j], wr3 = W_rel[3 * H + j];
    float wo0 = W_root[0 * H + j], wo1 = W_root[1 * H + j];
    float wo2 = W_root[2 * H + j], wo3 = W_root[3 * H + j];
    float b = b_rel[j];

    float mx = 0.0f;
    for (int n = n0; n < n1; ++n) {
        float4 a = ((const float4*)agg)[n];
        float inv = 1.0f / fmaxf(deg[n], 1.0f);
        const float* xr = nf + (size_t)n * 6;
        float v = b
                + (a.x * inv) * wr0 + (a.y * inv) * wr1
                + (a.z * inv) * wr2 + (a.w * inv) * wr3
                + xr[0] * wo0 + xr[1] * wo1 + xr[2] * wo2 + xr[3] * wo3;
        v = fmaxf(v, 0.0f);
        mx = fmaxf(mx, v);
        if (n == center) h0[j] = v;
    }
    atomicMax(xmax_bits + j, __float_as_uint(mx));  // relu out >= 0
}

// ---------------- tiny head MLP, one block ----------------
__global__ __launch_bounds__(256) void final_kernel(
        const float* __restrict__ nf,
        const int*   __restrict__ centerp,
        const unsigned int* __restrict__ xmax_bits,
        const float* __restrict__ h0,
        const float* __restrict__ W2,  const float* __restrict__ b2,
        const float* __restrict__ W21, const float* __restrict__ b21,
        const float* __restrict__ W1,  const float* __restrict__ b1,
        const float* __restrict__ W4,  const float* __restrict__ b4,
        float* __restrict__ out) {
    __shared__ float gin[H + MDH];
    __shared__ float md0[MDH];
    __shared__ float g1[L1D];
    int t = threadIdx.x;
    int center = *centerp;

    if (t < H) gin[t] = h0[t] - __uint_as_float(xmax_bits[t]);
    if (t < MDH) {
        float m0 = nf[(size_t)center * 6 + 4];
        float m1 = nf[(size_t)center * 6 + 5];
        md0[t] = fmaxf(m0 * W2[t] + m1 * W2[MDH + t] + b2[t], 0.0f);
    }
    __syncthreads();
    if (t < MDH) {
        float s = b21[t];
        for (int k = 0; k < MDH; ++k) s += md0[k] * W21[k * MDH + t];
        gin[H + t] = fmaxf(s, 0.0f);
    }
    __syncthreads();
    if (t < L1D) {
        float s = b1[t];
        for (int k = 0; k < H + MDH; ++k) s += gin[k] * W1[k * L1D + t];
        g1[t] = fmaxf(s, 0.0f);
    }
    __syncthreads();
    if (t < 5) {
        float s = b4[t];
        for (int k = 0; k < L1D; ++k) s += g1[k] * W4[k * 5 + t];
        out[t] = s;
    }
}

extern "C" void kernel_launch(void* const* d_in, const int* in_sizes, int n_in,
                              void* d_out, int out_size, void* d_ws, size_t ws_size,
                              hipStream_t stream) {
    const float* nf      = (const float*)d_in[0];
    const int*   ei      = (const int*)  d_in[1];
    const float* ew      = (const float*)d_in[2];
    const int*   centerp = (const int*)  d_in[3];
    const float* W_rel   = (const float*)d_in[4];
    const float* b_rel   = (const float*)d_in[5];
    const float* W_root  = (const float*)d_in[6];
    const float* W2      = (const float*)d_in[7];
    const float* b2      = (const float*)d_in[8];
    const float* W21     = (const float*)d_in[9];
    const float* b21     = (const float*)d_in[10];
    const float* W1      = (const float*)d_in[11];
    const float* b1      = (const float*)d_in[12];
    const float* W4      = (const float*)d_in[13];
    const float* b4      = (const float*)d_in[14];
    float* out = (float*)d_out;

    const int N = in_sizes[0] / 6;
    const int E = in_sizes[1] / 2;
    const int K = (N + BSZ - 1) >> BBITS;        // 782 for N=200000
    const int epb = (E + NB - 1) / NB;

    // workspace layout (4B units):
    // hist(K*NB) | tsum(K) | bstart(K+1) | agg(4N) | deg(N) | h0(H) | xmax(H) | sorted(2E)
    int*          hist   = (int*)d_ws;
    int*          tsum   = hist + (size_t)K * NB;
    int*          bstart = tsum + K;
    float*        agg    = (float*)(bstart + K + 1);
    float*        deg    = agg + (size_t)N * 4;
    float*        h0     = deg + N;
    unsigned int* xmax   = (unsigned int*)(h0 + H);
    uint2*        sorted = (uint2*)(xmax + H);

    size_t need = (size_t)((char*)(sorted + E) - (char*)d_ws);
    bool fast = (ws_size >= need) && (K <= KMAX) && (N < (1 << 24));

    if (fast) {
        zero_kernel<<<1, 256, 0, stream>>>((int*)xmax, H);
        hist_kernel<<<NB, 256, 0, stream>>>(ei, hist, E, K, epb);
        col_scan_kernel<<<K, 256, 0, stream>>>(hist, tsum);
        top_scan_kernel<<<1, 1024, 0, stream>>>(tsum, bstart, K);
        partition_kernel<<<NB, 256, 0, stream>>>(ei, ew, hist, bstart, sorted, E, K, epb);
        bucket_acc_kernel<<<K, 256, 0, stream>>>(nf, sorted, bstart, agg, deg, N);
    } else {
        // fallback: zero agg+deg (contiguous) + xmax, global-atomic scatter
        zero_kernel<<<(N * 5 + 255) / 256, 256, 0, stream>>>((int*)agg, N * 5);
        zero_kernel<<<1, 256, 0, stream>>>((int*)xmax, H);
        edge_atomic_kernel<<<(E + 255) / 256, 256, 0, stream>>>(nf, ei, ew, agg, deg, E);
    }

    const int blocks = 1024;
    const int npb = (N + blocks - 1) / blocks;
    node_kernel<<<blocks, 192, 0, stream>>>(nf, agg, deg, W_rel, b_rel, W_root,
                                            centerp, xmax, h0, N, npb);
    final_kernel<<<1, 256, 0, stream>>>(nf, centerp, xmax, h0,
                                        W2, b2, W21, b21, W1, b1, W4, b4, out);
}

// Round 6
// 600.606 us; speedup vs baseline: 2.9941x; 1.0459x over previous
//
#include <hip/hip_runtime.h>

#define H 184
#define MDH 16
#define L1D 188
#define BBITS 8
#define BSZ 256           // nodes per bucket (2^BBITS)
#define NB 1024           // blocks in hist/partition (must match in both)
#define KMAX 1024
#define SSUB 4            // sub-blocks per bucket in accumulate phase

// ---------------- zero init ----------------
__global__ void zero_kernel(int* __restrict__ p, int n) {
    int i = blockIdx.x * blockDim.x + threadIdx.x;
    if (i < n) p[i] = 0;
}

// ---------------- phase 1: per-block bucket histogram (LDS atomics only) ----------------
__global__ __launch_bounds__(256) void hist_kernel(
        const int* __restrict__ ei, int* __restrict__ hist, int E, int K, int epb) {
    __shared__ int cnt[KMAX];
    int b = blockIdx.x;
    for (int k = threadIdx.x; k < K; k += 256) cnt[k] = 0;
    __syncthreads();
    int e0 = b * epb;
    int e1 = min(E, e0 + epb);
    for (int e = e0 + threadIdx.x; e < e1; e += 256) {
        int dst = ei[E + e];
        atomicAdd(&cnt[dst >> BBITS], 1);
    }
    __syncthreads();
    for (int k = threadIdx.x; k < K; k += 256)
        hist[(size_t)k * NB + b] = cnt[k];
}

// ---------------- phase 2a: per-bucket exclusive scan over blocks ----------------
__global__ __launch_bounds__(256) void col_scan_kernel(
        int* __restrict__ hist, int* __restrict__ tsum) {
    __shared__ int s[256];
    int k = blockIdx.x;
    int t = threadIdx.x;
    int* row = hist + (size_t)k * NB;
    int cbase = 0;
    for (int c = 0; c < NB; c += 256) {
        int v = row[c + t];
        s[t] = v;
        __syncthreads();
        for (int st = 1; st < 256; st <<= 1) {
            int u = (t >= st) ? s[t - st] : 0;
            __syncthreads();
            s[t] += u;
            __syncthreads();
        }
        row[c + t] = s[t] - v + cbase;     // exclusive + carry
        int total = s[255];                // stable after last sync
        __syncthreads();                   // protect s before next chunk
        cbase += total;
    }
    if (t == 0) tsum[k] = cbase;
}

// ---------------- phase 2b: exclusive scan of bucket totals ----------------
__global__ __launch_bounds__(1024) void top_scan_kernel(
        const int* __restrict__ tsum, int* __restrict__ bstart, int K) {
    __shared__ int s[1024];
    int t = threadIdx.x;
    int v = (t < K) ? tsum[t] : 0;
    s[t] = v;
    __syncthreads();
    for (int st = 1; st < 1024; st <<= 1) {
        int u = (t >= st) ? s[t - st] : 0;
        __syncthreads();
        s[t] += u;
        __syncthreads();
    }
    if (t < K) bstart[t] = s[t] - v;
    if (t == K - 1) bstart[K] = s[t];
}

// ---------------- phase 3: partition edges into bucket runs ----------------
// Same block->edge-range mapping as hist_kernel. Slot allocation via LDS
// counters seeded from the scans — zero global atomics. Each block's write
// frontier is K lines (~50 KB) -> L2-resident -> stores merge.
__global__ __launch_bounds__(256) void partition_kernel(
        const int* __restrict__ ei, const float* __restrict__ ew,
        const int* __restrict__ hist, const int* __restrict__ bstart,
        uint2* __restrict__ sorted, int E, int K, int epb) {
    __shared__ int lcnt[KMAX];
    int b = blockIdx.x;
    for (int k = threadIdx.x; k < K; k += 256)
        lcnt[k] = bstart[k] + hist[(size_t)k * NB + b];
    __syncthreads();
    int e0 = b * epb;
    int e1 = min(E, e0 + epb);
    for (int e = e0 + threadIdx.x; e < e1; e += 256) {
        int dst = ei[E + e];
        int src = ei[e];
        float w = ew[e];
        int k = dst >> BBITS;
        int pos = atomicAdd(&lcnt[k], 1);
        sorted[pos] = make_uint2(((unsigned)(dst & (BSZ - 1)) << 24) | (unsigned)src,
                                 __float_as_uint(w));
    }
}

// ---------------- phase 4a: per-(bucket,sub) accumulate into LDS, emit partial ----------------
__global__ __launch_bounds__(256) void bucket_partial_kernel(
        const float* __restrict__ nf, const uint2* __restrict__ sorted,
        const int* __restrict__ bstart, float* __restrict__ partials) {
    __shared__ float acc[BSZ * 5];
    int k = blockIdx.x / SSUB;
    int s = blockIdx.x % SSUB;
    int t = threadIdx.x;
    for (int i = t; i < BSZ * 5; i += 256) acc[i] = 0.0f;
    __syncthreads();
    int r0 = bstart[k], r1 = bstart[k + 1];
    int len = r1 - r0;
    int i0 = r0 + (int)(((long long)len * s) / SSUB);
    int i1 = r0 + (int)(((long long)len * (s + 1)) / SSUB);
    for (int i = i0 + t; i < i1; i += 256) {
        uint2 r = sorted[i];
        unsigned src = r.x & 0xFFFFFFu;
        unsigned dl = r.x >> 24;
        float w = __uint_as_float(r.y);
        const float2* xr = (const float2*)(nf + (size_t)src * 6);
        float2 x01 = xr[0];
        float2 x23 = xr[1];
        float* a = acc + dl * 5;
        atomicAdd(a + 0, x01.x * w);
        atomicAdd(a + 1, x01.y * w);
        atomicAdd(a + 2, x23.x * w);
        atomicAdd(a + 3, x23.y * w);
        atomicAdd(a + 4, 1.0f);
    }
    __syncthreads();
    float* outp = partials + (size_t)blockIdx.x * (BSZ * 5);
    for (int i = t; i < BSZ * 5; i += 256) outp[i] = acc[i];
}

// ---------------- phase 4b: reduce partials -> agg, deg ----------------
__global__ __launch_bounds__(256) void bucket_reduce_kernel(
        const float* __restrict__ partials, float* __restrict__ agg,
        float* __restrict__ deg, int N) {
    __shared__ float acc[BSZ * 5];
    int k = blockIdx.x;
    int t = threadIdx.x;
    const float* base = partials + (size_t)k * SSUB * (BSZ * 5);
    for (int j = t; j < BSZ * 5; j += 256) {
        float v = 0.0f;
        for (int s = 0; s < SSUB; ++s) v += base[(size_t)s * (BSZ * 5) + j];
        acc[j] = v;
    }
    __syncthreads();
    int n = (k << BBITS) + t;
    if (n < N) {
        ((float4*)agg)[n] = make_float4(acc[t * 5], acc[t * 5 + 1],
                                        acc[t * 5 + 2], acc[t * 5 + 3]);
        deg[n] = acc[t * 5 + 4];
    }
}

// ---------------- fallback: global-atomic scatter (ws too small / K too big) ----------------
__global__ __launch_bounds__(256) void edge_atomic_kernel(
        const float* __restrict__ nf, const int* __restrict__ ei,
        const float* __restrict__ ew, float* __restrict__ agg,
        float* __restrict__ deg, int E) {
    int e = blockIdx.x * blockDim.x + threadIdx.x;
    if (e >= E) return;
    int src = ei[e];
    int dst = ei[E + e];
    float w = ew[e];
    const float2* xr = (const float2*)(nf + (size_t)src * 6);
    float2 x01 = xr[0];
    float2 x23 = xr[1];
    float* a = agg + (size_t)dst * 4;
    atomicAdd(a + 0, x01.x * w);
    atomicAdd(a + 1, x01.y * w);
    atomicAdd(a + 2, x23.x * w);
    atomicAdd(a + 3, x23.y * w);
    atomicAdd(deg + dst, 1.0f);
}

// ---------------- per-node dense layer + global feature max ----------------
__global__ __launch_bounds__(192) void node_kernel(
        const float* __restrict__ nf,
        const float* __restrict__ agg,
        const float* __restrict__ deg,
        const float* __restrict__ W_rel, const float* __restrict__ b_rel,
        const float* __restrict__ W_root,
        const int*   __restrict__ centerp,
        unsigned int* __restrict__ xmax_bits,
        float* __restrict__ h0,
        int N, int nodes_per_block) {
    int j = threadIdx.x;
    if (j >= H) return;
    int center = *centerp;
    int n0 = blockIdx.x * nodes_per_block;
    int n1 = n0 + nodes_per_block;
    if (n1 > N) n1 = N;

    float wr0 = W_rel[0 * H + j], wr1 = W_rel[1 * H + j];
    float wr2 = W_rel[2 * H + j], wr3 = W_rel[3 * H + j];
    float wo0 = W_root[0 * H + j], wo1 = W_root[1 * H + j];
    float wo2 = W_root[2 * H + j], wo3 = W_root[3 * H + j];
    float b = b_rel[j];

    float mx = 0.0f;
    for (int n = n0; n < n1; ++n) {
        float4 a = ((const float4*)agg)[n];
        float inv = 1.0f / fmaxf(deg[n], 1.0f);
        const float* xr = nf + (size_t)n * 6;
        float v = b
                + (a.x * inv) * wr0 + (a.y * inv) * wr1
                + (a.z * inv) * wr2 + (a.w * inv) * wr3
                + xr[0] * wo0 + xr[1] * wo1 + xr[2] * wo2 + xr[3] * wo3;
        v = fmaxf(v, 0.0f);
        mx = fmaxf(mx, v);
        if (n == center) h0[j] = v;
    }
    atomicMax(xmax_bits + j, __float_as_uint(mx));  // relu out >= 0
}

// ---------------- tiny head MLP, one block ----------------
__global__ __launch_bounds__(256) void final_kernel(
        const float* __restrict__ nf,
        const int*   __restrict__ centerp,
        const unsigned int* __restrict__ xmax_bits,
        const float* __restrict__ h0,
        const float* __restrict__ W2,  const float* __restrict__ b2,
        const float* __restrict__ W21, const float* __restrict__ b21,
        const float* __restrict__ W1,  const float* __restrict__ b1,
        const float* __restrict__ W4,  const float* __restrict__ b4,
        float* __restrict__ out) {
    __shared__ float gin[H + MDH];
    __shared__ float md0[MDH];
    __shared__ float g1[L1D];
    int t = threadIdx.x;
    int center = *centerp;

    if (t < H) gin[t] = h0[t] - __uint_as_float(xmax_bits[t]);
    if (t < MDH) {
        float m0 = nf[(size_t)center * 6 + 4];
        float m1 = nf[(size_t)center * 6 + 5];
        md0[t] = fmaxf(m0 * W2[t] + m1 * W2[MDH + t] + b2[t], 0.0f);
    }
    __syncthreads();
    if (t < MDH) {
        float s = b21[t];
        for (int k = 0; k < MDH; ++k) s += md0[k] * W21[k * MDH + t];
        gin[H + t] = fmaxf(s, 0.0f);
    }
    __syncthreads();
    if (t < L1D) {
        float s = b1[t];
        for (int k = 0; k < H + MDH; ++k) s += gin[k] * W1[k * L1D + t];
        g1[t] = fmaxf(s, 0.0f);
    }
    __syncthreads();
    if (t < 5) {
        float s = b4[t];
        for (int k = 0; k < L1D; ++k) s += g1[k] * W4[k * 5 + t];
        out[t] = s;
    }
}

extern "C" void kernel_launch(void* const* d_in, const int* in_sizes, int n_in,
                              void* d_out, int out_size, void* d_ws, size_t ws_size,
                              hipStream_t stream) {
    const float* nf      = (const float*)d_in[0];
    const int*   ei      = (const int*)  d_in[1];
    const float* ew      = (const float*)d_in[2];
    const int*   centerp = (const int*)  d_in[3];
    const float* W_rel   = (const float*)d_in[4];
    const float* b_rel   = (const float*)d_in[5];
    const float* W_root  = (const float*)d_in[6];
    const float* W2      = (const float*)d_in[7];
    const float* b2      = (const float*)d_in[8];
    const float* W21     = (const float*)d_in[9];
    const float* b21     = (const float*)d_in[10];
    const float* W1      = (const float*)d_in[11];
    const float* b1      = (const float*)d_in[12];
    const float* W4      = (const float*)d_in[13];
    const float* b4      = (const float*)d_in[14];
    float* out = (float*)d_out;

    const int N = in_sizes[0] / 6;
    const int E = in_sizes[1] / 2;
    const int K = (N + BSZ - 1) >> BBITS;        // 782 for N=200000
    const int epb = (E + NB - 1) / NB;

    // workspace layout (4B units):
    // hist(K*NB) | tsum(K) | bstart(K+1) | agg(4N) | deg(N) | h0(H) | xmax(H)
    //   | partials(K*SSUB*1280) | sorted(2E)
    int*          hist     = (int*)d_ws;
    int*          tsum     = hist + (size_t)K * NB;
    int*          bstart   = tsum + K;
    float*        agg      = (float*)(bstart + K + 1);
    float*        deg      = agg + (size_t)N * 4;
    float*        h0       = deg + N;
    unsigned int* xmax     = (unsigned int*)(h0 + H);
    float*        partials = (float*)(xmax + H);
    uint2*        sorted   = (uint2*)(partials + (size_t)K * SSUB * (BSZ * 5));

    size_t need = (size_t)((char*)(sorted + E) - (char*)d_ws);
    bool fast = (ws_size >= need) && (K <= KMAX) && (N < (1 << 24));

    if (fast) {
        zero_kernel<<<1, 256, 0, stream>>>((int*)xmax, H);
        hist_kernel<<<NB, 256, 0, stream>>>(ei, hist, E, K, epb);
        col_scan_kernel<<<K, 256, 0, stream>>>(hist, tsum);
        top_scan_kernel<<<1, 1024, 0, stream>>>(tsum, bstart, K);
        partition_kernel<<<NB, 256, 0, stream>>>(ei, ew, hist, bstart, sorted, E, K, epb);
        bucket_partial_kernel<<<K * SSUB, 256, 0, stream>>>(nf, sorted, bstart, partials);
        bucket_reduce_kernel<<<K, 256, 0, stream>>>(partials, agg, deg, N);
    } else {
        // fallback: zero agg+deg (contiguous) + xmax, global-atomic scatter
        zero_kernel<<<(N * 5 + 255) / 256, 256, 0, stream>>>((int*)agg, N * 5);
        zero_kernel<<<1, 256, 0, stream>>>((int*)xmax, H);
        edge_atomic_kernel<<<(E + 255) / 256, 256, 0, stream>>>(nf, ei, ew, agg, deg, E);
    }

    const int blocks = 1024;
    const int npb = (N + blocks - 1) / blocks;
    node_kernel<<<blocks, 192, 0, stream>>>(nf, agg, deg, W_rel, b_rel, W_root,
                                            centerp, xmax, h0, N, npb);
    final_kernel<<<1, 256, 0, stream>>>(nf, centerp, xmax, h0,
                                        W2, b2, W21, b21, W1, b1, W4, b4, out);
}

// Round 7
// 582.715 us; speedup vs baseline: 3.0860x; 1.0307x over previous
//
#include <hip/hip_runtime.h>

#define H 184
#define MDH 16
#define L1D 188
#define BBITS 8
#define BSZ 256           // nodes per bucket (2^BBITS)
#define NB 512            // blocks in hist/partition (must match in both)
#define KMAX 1024
#define SSUB 4            // sub-blocks per bucket in accumulate phase

// ---------------- zero init ----------------
__global__ void zero_kernel(int* __restrict__ p, int n) {
    int i = blockIdx.x * blockDim.x + threadIdx.x;
    if (i < n) p[i] = 0;
}

// ---------------- pack nf[:, :4] into float4 table (coalesced via LDS) ----------------
__global__ __launch_bounds__(256) void pack_kernel(
        const float* __restrict__ nf, float4* __restrict__ x4, int N) {
    __shared__ float s[256 * 6];
    int base = blockIdx.x * 256;            // first node of this block
    int t = threadIdx.x;
    // read 1536 contiguous floats
    for (int i = t; i < 256 * 6; i += 256) {
        int gi = base * 6 + i;
        s[i] = (gi < N * 6) ? nf[gi] : 0.0f;
    }
    __syncthreads();
    int n = base + t;
    if (n < N)
        x4[n] = make_float4(s[t * 6], s[t * 6 + 1], s[t * 6 + 2], s[t * 6 + 3]);
}

// ---------------- phase 1: per-block bucket histogram (LDS atomics only) ----------------
__global__ __launch_bounds__(256) void hist_kernel(
        const int* __restrict__ ei, int* __restrict__ hist, int E, int K, int epb) {
    __shared__ int cnt[KMAX];
    int b = blockIdx.x;
    for (int k = threadIdx.x; k < K; k += 256) cnt[k] = 0;
    __syncthreads();
    int e0 = b * epb;
    int e1 = min(E, e0 + epb);
    for (int e = e0 + threadIdx.x; e < e1; e += 256) {
        int dst = ei[E + e];
        atomicAdd(&cnt[dst >> BBITS], 1);
    }
    __syncthreads();
    for (int k = threadIdx.x; k < K; k += 256)
        hist[(size_t)k * NB + b] = cnt[k];
}

// ---------------- phase 2a: per-bucket exclusive scan over blocks ----------------
__global__ __launch_bounds__(256) void col_scan_kernel(
        int* __restrict__ hist, int* __restrict__ tsum) {
    __shared__ int s[256];
    int k = blockIdx.x;
    int t = threadIdx.x;
    int* row = hist + (size_t)k * NB;
    int cbase = 0;
    for (int c = 0; c < NB; c += 256) {
        int v = row[c + t];
        s[t] = v;
        __syncthreads();
        for (int st = 1; st < 256; st <<= 1) {
            int u = (t >= st) ? s[t - st] : 0;
            __syncthreads();
            s[t] += u;
            __syncthreads();
        }
        row[c + t] = s[t] - v + cbase;     // exclusive + carry
        int total = s[255];                // stable after last sync
        __syncthreads();                   // protect s before next chunk
        cbase += total;
    }
    if (t == 0) tsum[k] = cbase;
}

// ---------------- phase 2b: exclusive scan of bucket totals ----------------
__global__ __launch_bounds__(1024) void top_scan_kernel(
        const int* __restrict__ tsum, int* __restrict__ bstart, int K) {
    __shared__ int s[1024];
    int t = threadIdx.x;
    int v = (t < K) ? tsum[t] : 0;
    s[t] = v;
    __syncthreads();
    for (int st = 1; st < 1024; st <<= 1) {
        int u = (t >= st) ? s[t - st] : 0;
        __syncthreads();
        s[t] += u;
        __syncthreads();
    }
    if (t < K) bstart[t] = s[t] - v;
    if (t == K - 1) bstart[K] = s[t];
}

// ---------------- phase 3: partition edges into bucket runs ----------------
// Same block->edge-range mapping as hist_kernel. NB=512 -> ~16 records per
// (block,bucket) = 2 full 64B lines; resident frontier per XCD ~3.2 MB <= L2
// so scattered stores merge before eviction.
__global__ __launch_bounds__(256) void partition_kernel(
        const int* __restrict__ ei, const float* __restrict__ ew,
        const int* __restrict__ hist, const int* __restrict__ bstart,
        uint2* __restrict__ sorted, int E, int K, int epb) {
    __shared__ int lcnt[KMAX];
    int b = blockIdx.x;
    for (int k = threadIdx.x; k < K; k += 256)
        lcnt[k] = bstart[k] + hist[(size_t)k * NB + b];
    __syncthreads();
    int e0 = b * epb;
    int e1 = min(E, e0 + epb);
    for (int e = e0 + threadIdx.x; e < e1; e += 256) {
        int dst = ei[E + e];
        int src = ei[e];
        float w = ew[e];
        int k = dst >> BBITS;
        int pos = atomicAdd(&lcnt[k], 1);
        sorted[pos] = make_uint2(((unsigned)(dst & (BSZ - 1)) << 24) | (unsigned)src,
                                 __float_as_uint(w));
    }
}

// ---------------- phase 4a: per-(bucket,sub) accumulate into LDS, emit partial ----------------
// 2-deep pipeline: each thread handles records i and i+256 -> two independent
// record loads + two independent float4 gathers in flight per iteration.
__global__ __launch_bounds__(256) void bucket_partial_kernel(
        const float4* __restrict__ x4, const uint2* __restrict__ sorted,
        const int* __restrict__ bstart, float* __restrict__ partials) {
    __shared__ float acc[BSZ * 5];
    int k = blockIdx.x / SSUB;
    int s = blockIdx.x % SSUB;
    int t = threadIdx.x;
    for (int i = t; i < BSZ * 5; i += 256) acc[i] = 0.0f;
    __syncthreads();
    int r0 = bstart[k], r1 = bstart[k + 1];
    int len = r1 - r0;
    int i0 = r0 + (int)(((long long)len * s) / SSUB);
    int i1 = r0 + (int)(((long long)len * (s + 1)) / SSUB);
    for (int i = i0 + t; i < i1; i += 512) {
        int j = i + 256;
        bool has2 = (j < i1);
        uint2 ra = sorted[i];
        uint2 rb = has2 ? sorted[j] : make_uint2(0u, 0u);
        float4 xa = x4[ra.x & 0xFFFFFFu];
        float4 xb = x4[rb.x & 0xFFFFFFu];
        float wa = __uint_as_float(ra.y);
        float* a = acc + (ra.x >> 24) * 5;
        atomicAdd(a + 0, xa.x * wa);
        atomicAdd(a + 1, xa.y * wa);
        atomicAdd(a + 2, xa.z * wa);
        atomicAdd(a + 3, xa.w * wa);
        atomicAdd(a + 4, 1.0f);
        if (has2) {
            float wb = __uint_as_float(rb.y);
            float* b2 = acc + (rb.x >> 24) * 5;
            atomicAdd(b2 + 0, xb.x * wb);
            atomicAdd(b2 + 1, xb.y * wb);
            atomicAdd(b2 + 2, xb.z * wb);
            atomicAdd(b2 + 3, xb.w * wb);
            atomicAdd(b2 + 4, 1.0f);
        }
    }
    __syncthreads();
    float* outp = partials + (size_t)blockIdx.x * (BSZ * 5);
    for (int i = t; i < BSZ * 5; i += 256) outp[i] = acc[i];
}

// ---------------- phase 4b: reduce partials -> agg, deg ----------------
__global__ __launch_bounds__(256) void bucket_reduce_kernel(
        const float* __restrict__ partials, float* __restrict__ agg,
        float* __restrict__ deg, int N) {
    __shared__ float acc[BSZ * 5];
    int k = blockIdx.x;
    int t = threadIdx.x;
    const float* base = partials + (size_t)k * SSUB * (BSZ * 5);
    for (int j = t; j < BSZ * 5; j += 256) {
        float v = 0.0f;
        for (int s = 0; s < SSUB; ++s) v += base[(size_t)s * (BSZ * 5) + j];
        acc[j] = v;
    }
    __syncthreads();
    int n = (k << BBITS) + t;
    if (n < N) {
        ((float4*)agg)[n] = make_float4(acc[t * 5], acc[t * 5 + 1],
                                        acc[t * 5 + 2], acc[t * 5 + 3]);
        deg[n] = acc[t * 5 + 4];
    }
}

// ---------------- fallback: global-atomic scatter (ws too small / K too big) ----------------
__global__ __launch_bounds__(256) void edge_atomic_kernel(
        const float* __restrict__ nf, const int* __restrict__ ei,
        const float* __restrict__ ew, float* __restrict__ agg,
        float* __restrict__ deg, int E) {
    int e = blockIdx.x * blockDim.x + threadIdx.x;
    if (e >= E) return;
    int src = ei[e];
    int dst = ei[E + e];
    float w = ew[e];
    const float2* xr = (const float2*)(nf + (size_t)src * 6);
    float2 x01 = xr[0];
    float2 x23 = xr[1];
    float* a = agg + (size_t)dst * 4;
    atomicAdd(a + 0, x01.x * w);
    atomicAdd(a + 1, x01.y * w);
    atomicAdd(a + 2, x23.x * w);
    atomicAdd(a + 3, x23.y * w);
    atomicAdd(deg + dst, 1.0f);
}

// ---------------- per-node dense layer + global feature max ----------------
__global__ __launch_bounds__(192) void node_kernel(
        const float4* __restrict__ x4,
        const float* __restrict__ agg,
        const float* __restrict__ deg,
        const float* __restrict__ W_rel, const float* __restrict__ b_rel,
        const float* __restrict__ W_root,
        const int*   __restrict__ centerp,
        unsigned int* __restrict__ xmax_bits,
        float* __restrict__ h0,
        int N, int nodes_per_block) {
    int j = threadIdx.x;
    if (j >= H) return;
    int center = *centerp;
    int n0 = blockIdx.x * nodes_per_block;
    int n1 = n0 + nodes_per_block;
    if (n1 > N) n1 = N;

    float wr0 = W_rel[0 * H + j], wr1 = W_rel[1 * H + j];
    float wr2 = W_rel[2 * H + j], wr3 = W_rel[3 * H + j];
    float wo0 = W_root[0 * H + j], wo1 = W_root[1 * H + j];
    float wo2 = W_root[2 * H + j], wo3 = W_root[3 * H + j];
    float b = b_rel[j];

    float mx = 0.0f;
    for (int n = n0; n < n1; ++n) {
        float4 a = ((const float4*)agg)[n];
        float inv = 1.0f / fmaxf(deg[n], 1.0f);
        float4 x = x4[n];
        float v = b
                + (a.x * inv) * wr0 + (a.y * inv) * wr1
                + (a.z * inv) * wr2 + (a.w * inv) * wr3
                + x.x * wo0 + x.y * wo1 + x.z * wo2 + x.w * wo3;
        v = fmaxf(v, 0.0f);
        mx = fmaxf(mx, v);
        if (n == center) h0[j] = v;
    }
    atomicMax(xmax_bits + j, __float_as_uint(mx));  // relu out >= 0
}

// ---------------- tiny head MLP, one block ----------------
__global__ __launch_bounds__(256) void final_kernel(
        const float* __restrict__ nf,
        const int*   __restrict__ centerp,
        const unsigned int* __restrict__ xmax_bits,
        const float* __restrict__ h0,
        const float* __restrict__ W2,  const float* __restrict__ b2,
        const float* __restrict__ W21, const float* __restrict__ b21,
        const float* __restrict__ W1,  const float* __restrict__ b1,
        const float* __restrict__ W4,  const float* __restrict__ b4,
        float* __restrict__ out) {
    __shared__ float gin[H + MDH];
    __shared__ float md0[MDH];
    __shared__ float g1[L1D];
    int t = threadIdx.x;
    int center = *centerp;

    if (t < H) gin[t] = h0[t] - __uint_as_float(xmax_bits[t]);
    if (t < MDH) {
        float m0 = nf[(size_t)center * 6 + 4];
        float m1 = nf[(size_t)center * 6 + 5];
        md0[t] = fmaxf(m0 * W2[t] + m1 * W2[MDH + t] + b2[t], 0.0f);
    }
    __syncthreads();
    if (t < MDH) {
        float s = b21[t];
        for (int k = 0; k < MDH; ++k) s += md0[k] * W21[k * MDH + t];
        gin[H + t] = fmaxf(s, 0.0f);
    }
    __syncthreads();
    if (t < L1D) {
        float s = b1[t];
        for (int k = 0; k < H + MDH; ++k) s += gin[k] * W1[k * L1D + t];
        g1[t] = fmaxf(s, 0.0f);
    }
    __syncthreads();
    if (t < 5) {
        float s = b4[t];
        for (int k = 0; k < L1D; ++k) s += g1[k] * W4[k * 5 + t];
        out[t] = s;
    }
}

extern "C" void kernel_launch(void* const* d_in, const int* in_sizes, int n_in,
                              void* d_out, int out_size, void* d_ws, size_t ws_size,
                              hipStream_t stream) {
    const float* nf      = (const float*)d_in[0];
    const int*   ei      = (const int*)  d_in[1];
    const float* ew      = (const float*)d_in[2];
    const int*   centerp = (const int*)  d_in[3];
    const float* W_rel   = (const float*)d_in[4];
    const float* b_rel   = (const float*)d_in[5];
    const float* W_root  = (const float*)d_in[6];
    const float* W2      = (const float*)d_in[7];
    const float* b2      = (const float*)d_in[8];
    const float* W21     = (const float*)d_in[9];
    const float* b21     = (const float*)d_in[10];
    const float* W1      = (const float*)d_in[11];
    const float* b1      = (const float*)d_in[12];
    const float* W4      = (const float*)d_in[13];
    const float* b4      = (const float*)d_in[14];
    float* out = (float*)d_out;

    const int N = in_sizes[0] / 6;
    const int E = in_sizes[1] / 2;
    const int K = (N + BSZ - 1) >> BBITS;        // 782 for N=200000
    const int epb = (E + NB - 1) / NB;

    // workspace layout (4B units):
    // hist(K*NB) | tsum(K) | bstart(K+1) | agg(4N) | deg(N) | h0(H) | xmax(H)
    //   | x4(4N) | partials(K*SSUB*1280) | sorted(2E)
    int*          hist     = (int*)d_ws;
    int*          tsum     = hist + (size_t)K * NB;
    int*          bstart   = tsum + K;
    float*        agg      = (float*)(bstart + K + 1);
    float*        deg      = agg + (size_t)N * 4;
    float*        h0       = deg + N;
    unsigned int* xmax     = (unsigned int*)(h0 + H);
    float4*       x4       = (float4*)(xmax + H);
    float*        partials = (float*)(x4 + N);
    uint2*        sorted   = (uint2*)(partials + (size_t)K * SSUB * (BSZ * 5));

    size_t need = (size_t)((char*)(sorted + E) - (char*)d_ws);
    bool fast = (ws_size >= need) && (K <= KMAX) && (N < (1 << 24));

    if (fast) {
        zero_kernel<<<1, 256, 0, stream>>>((int*)xmax, H);
        pack_kernel<<<(N + 255) / 256, 256, 0, stream>>>(nf, x4, N);
        hist_kernel<<<NB, 256, 0, stream>>>(ei, hist, E, K, epb);
        col_scan_kernel<<<K, 256, 0, stream>>>(hist, tsum);
        top_scan_kernel<<<1, 1024, 0, stream>>>(tsum, bstart, K);
        partition_kernel<<<NB, 256, 0, stream>>>(ei, ew, hist, bstart, sorted, E, K, epb);
        bucket_partial_kernel<<<K * SSUB, 256, 0, stream>>>(x4, sorted, bstart, partials);
        bucket_reduce_kernel<<<K, 256, 0, stream>>>(partials, agg, deg, N);

        const int blocks = 1024;
        const int npb = (N + blocks - 1) / blocks;
        node_kernel<<<blocks, 192, 0, stream>>>(x4, agg, deg, W_rel, b_rel, W_root,
                                                centerp, xmax, h0, N, npb);
    } else {
        // fallback: zero agg+deg (contiguous) + xmax, global-atomic scatter
        zero_kernel<<<(N * 5 + 255) / 256, 256, 0, stream>>>((int*)agg, N * 5);
        zero_kernel<<<1, 256, 0, stream>>>((int*)xmax, H);
        pack_kernel<<<(N + 255) / 256, 256, 0, stream>>>(nf, x4, N);
        edge_atomic_kernel<<<(E + 255) / 256, 256, 0, stream>>>(nf, ei, ew, agg, deg, E);
        const int blocks = 1024;
        const int npb = (N + blocks - 1) / blocks;
        node_kernel<<<blocks, 192, 0, stream>>>(x4, agg, deg, W_rel, b_rel, W_root,
                                                centerp, xmax, h0, N, npb);
    }

    final_kernel<<<1, 256, 0, stream>>>(nf, centerp, xmax, h0,
                                        W2, b2, W21, b21, W1, b1, W4, b4, out);
}